// Round 1
// baseline (10467.392 us; speedup 1.0000x reference)
//
#include <hip/hip_runtime.h>
#include <math.h>
#include <climits>

#define SQ 4096          // sequence length
#define HD 1024          // hidden
#define PD 4096          // pool size
#define DD 512           // pool dim
#define MR 16384         // B*S rows
#define INTERD 1024

// ---------------------------------------------------------------------------
// Tiled fp32 GEMM: C[row, n] = EPI( sum_k A[row,k]*B[n,k] + bias[n] )
// Tile 64x64, BK=16, 256 threads, 4x4 per thread.
// AMODE 0: plain A[(row-arow0)*lda + k]
// AMODE 1: dilated-conv gather from x: k-index c -> (tap=c/1024, cin=c%1024),
//          reads x[b, s+(tap-1)*dil, cin] with zero pad (row=(b,s) global).
// BMODE 0: plain B[n*ldb + k]
// BMODE 1: conv_w gather: B[n*3072 + cin*3 + tap]
// EPI 0 none, 1 relu, 2 gelu(erf), 3 per-row top-2 candidates (raw logits)
// ---------------------------------------------------------------------------
template<int AMODE, int BMODE, int EPI>
__global__ __launch_bounds__(256)
void gemm_k(const float* __restrict__ A, int lda, int arow0,
            const float* __restrict__ Bm, int ldb,
            const float* __restrict__ bias,
            float* __restrict__ C, int ldc, int coff, int crow0,
            int K, int row0, int dil,
            float* __restrict__ cand_v, int* __restrict__ cand_i)
{
    __shared__ float As[16][68];   // pad 68: stride%4==0 -> aligned b128, 2-way banks (free)
    __shared__ float Bs[16][68];
    const int tid = threadIdx.x;
    const int tx = tid & 15;
    const int ty = tid >> 4;
    const int bm = row0 + blockIdx.y * 64;
    const int bn = blockIdx.x * 64;

    float acc[4][4];
#pragma unroll
    for (int i = 0; i < 4; ++i)
#pragma unroll
        for (int j = 0; j < 4; ++j) acc[i][j] = 0.f;

    for (int kt = 0; kt < K; kt += 16) {
#pragma unroll
        for (int l = 0; l < 4; ++l) {
            int idx = tid + l * 256;      // 0..1023 over (r, c), c fastest
            int r = idx >> 4;
            int c = idx & 15;
            float va;
            if (AMODE == 0) {
                va = A[(size_t)(bm + r - arow0) * lda + (kt + c)];
            } else {
                int row = bm + r;
                int b = row >> 12;            // row / 4096
                int s = row & (SQ - 1);
                int cc = kt + c;
                int tap = cc >> 10;           // 0..2
                int cin = cc & (HD - 1);
                int sp = s + (tap - 1) * dil;
                va = (sp >= 0 && sp < SQ) ? A[((size_t)b * SQ + sp) * HD + cin] : 0.f;
            }
            As[c][r] = va;
            float vb;
            if (BMODE == 0) {
                vb = Bm[(size_t)(bn + r) * ldb + (kt + c)];
            } else {
                int cc = kt + c;
                int tap = cc >> 10;
                int cin = cc & (HD - 1);
                vb = Bm[(size_t)(bn + r) * 3072 + cin * 3 + tap];
            }
            Bs[c][r] = vb;
        }
        __syncthreads();
#pragma unroll
        for (int c = 0; c < 16; ++c) {
            float a[4], b[4];
#pragma unroll
            for (int i = 0; i < 4; ++i) a[i] = As[c][ty * 4 + i];
#pragma unroll
            for (int j = 0; j < 4; ++j) b[j] = Bs[c][tx * 4 + j];
#pragma unroll
            for (int i = 0; i < 4; ++i)
#pragma unroll
                for (int j = 0; j < 4; ++j)
                    acc[i][j] = fmaf(a[i], b[j], acc[i][j]);
        }
        __syncthreads();
    }

    if constexpr (EPI == 3) {
        // per-row top-2 within this 64-column tile, ranked on RAW logits
        __shared__ float lv[64][16][2];
        __shared__ int   li[64][16][2];
#pragma unroll
        for (int i = 0; i < 4; ++i) {
            int rl = ty * 4 + i;
            float bv0 = -1e30f, bv1 = -1e30f; int bi0 = INT_MAX, bi1 = INT_MAX;
#pragma unroll
            for (int j = 0; j < 4; ++j) {
                int n = bn + tx * 4 + j;
                float v = acc[i][j] + bias[n];
                if (v > bv0 || (v == bv0 && n < bi0)) { bv1 = bv0; bi1 = bi0; bv0 = v; bi0 = n; }
                else if (v > bv1 || (v == bv1 && n < bi1)) { bv1 = v; bi1 = n; }
            }
            lv[rl][tx][0] = bv0; lv[rl][tx][1] = bv1;
            li[rl][tx][0] = bi0; li[rl][tx][1] = bi1;
        }
        __syncthreads();
        if (tid < 64) {
            float bv0 = -1e30f, bv1 = -1e30f; int bi0 = INT_MAX, bi1 = INT_MAX;
            for (int q = 0; q < 16; ++q) {
#pragma unroll
                for (int u = 0; u < 2; ++u) {
                    float v = lv[tid][q][u]; int n = li[tid][q][u];
                    if (v > bv0 || (v == bv0 && n < bi0)) { bv1 = bv0; bi1 = bi0; bv0 = v; bi0 = n; }
                    else if (v > bv1 || (v == bv1 && n < bi1)) { bv1 = v; bi1 = n; }
                }
            }
            size_t base = (size_t)(bm + tid) * 128 + (size_t)blockIdx.x * 2;
            cand_v[base] = bv0; cand_v[base + 1] = bv1;
            cand_i[base] = bi0; cand_i[base + 1] = bi1;
        }
    } else {
#pragma unroll
        for (int i = 0; i < 4; ++i) {
#pragma unroll
            for (int j = 0; j < 4; ++j) {
                int n = bn + tx * 4 + j;
                float v = acc[i][j] + bias[n];
                if (EPI == 1) v = fmaxf(v, 0.f);
                if (EPI == 2) v = 0.5f * v * (1.0f + erff(v * 0.70710678118654752f));
                C[(size_t)(bm + ty * 4 + i - crow0) * ldc + coff + n] = v;
            }
        }
    }
}

// merge per-tile candidates -> global top-2; softmax weights; usage atomics;
// weighted_map gather into combined[:, 512:1024]
__global__ __launch_bounds__(64)
void merge_k(const float* __restrict__ cand_v, const int* __restrict__ cand_i,
             const float* __restrict__ pool, const float* __restrict__ tptr,
             float* __restrict__ combined, float* __restrict__ usage)
{
    int row = blockIdx.x;
    int t = threadIdx.x;
    __shared__ float sv[128];
    __shared__ int   si[128];
    sv[t]      = cand_v[(size_t)row * 128 + t];
    sv[t + 64] = cand_v[(size_t)row * 128 + 64 + t];
    si[t]      = cand_i[(size_t)row * 128 + t];
    si[t + 64] = cand_i[(size_t)row * 128 + 64 + t];
    __syncthreads();
    __shared__ float wsh[2];
    __shared__ int   ish[2];
    if (t == 0) {
        float bv0 = -1e30f, bv1 = -1e30f; int bi0 = INT_MAX, bi1 = INT_MAX;
        for (int q = 0; q < 128; ++q) {
            float v = sv[q]; int n = si[q];
            if (v > bv0 || (v == bv0 && n < bi0)) { bv1 = bv0; bi1 = bi0; bv0 = v; bi0 = n; }
            else if (v > bv1 || (v == bv1 && n < bi1)) { bv1 = v; bi1 = n; }
        }
        float tc = fminf(fmaxf(tptr[0], 0.1f), 5.0f);
        float v0 = fminf(fmaxf(bv0 / tc, -10.f), 10.f);
        float v1 = fminf(fmaxf(bv1 / tc, -10.f), 10.f);
        float e1 = expf(v1 - v0);
        float w0 = 1.f / (1.f + e1);
        float w1 = e1 / (1.f + e1);
        atomicAdd(&usage[bi0], w0);
        atomicAdd(&usage[bi1], w1);
        wsh[0] = w0; wsh[1] = w1; ish[0] = bi0; ish[1] = bi1;
    }
    __syncthreads();
    float w0 = wsh[0], w1 = wsh[1];
    const float* p0 = pool + (size_t)ish[0] * DD;
    const float* p1 = pool + (size_t)ish[1] * DD;
    float* dst = combined + (size_t)row * 1024 + 512;
    for (int j = t; j < DD; j += 64) dst[j] = w0 * p0[j] + w1 * p1[j];
}

// in-place layernorm over combined[:, 0:512]
__global__ __launch_bounds__(256)
void ln_k(float* __restrict__ combined, const float* __restrict__ g,
          const float* __restrict__ b)
{
    int row = blockIdx.x;
    int t = threadIdx.x;
    float* p = combined + (size_t)row * 1024;
    float x0 = p[t], x1 = p[t + 256];
    __shared__ float s1[256], s2[256];
    s1[t] = x0 + x1;
    s2[t] = x0 * x0 + x1 * x1;
    __syncthreads();
    for (int o = 128; o > 0; o >>= 1) {
        if (t < o) { s1[t] += s1[t + o]; s2[t] += s2[t + o]; }
        __syncthreads();
    }
    float mu = s1[0] * (1.0f / 512.0f);
    float var = s2[0] * (1.0f / 512.0f) - mu * mu;
    float inv = rsqrtf(var + 1e-5f);
    p[t]       = (x0 - mu) * inv * g[t] + b[t];
    p[t + 256] = (x1 - mu) * inv * g[t + 256] + b[t + 256];
}

__global__ __launch_bounds__(256)
void gate_k(const float* __restrict__ x, const float* __restrict__ wg,
            const float* __restrict__ bg, float* __restrict__ gate)
{
    int row = blockIdx.x;
    int t = threadIdx.x;
    const float* p = x + (size_t)row * HD;
    float s = p[t] * wg[t] + p[t + 256] * wg[t + 256]
            + p[t + 512] * wg[t + 512] + p[t + 768] * wg[t + 768];
    __shared__ float s1[256];
    s1[t] = s;
    __syncthreads();
    for (int o = 128; o > 0; o >>= 1) {
        if (t < o) s1[t] += s1[t + o];
        __syncthreads();
    }
    if (t == 0) gate[row] = 1.f / (1.f + expf(-(s1[0] + bg[0])));
}

// out = gate*local + (1-gate)*out   (out already holds global_out), chunk rows
__global__ __launch_bounds__(256)
void combine_k(const float* __restrict__ localc, const float* __restrict__ gate,
               float* __restrict__ out, int row0)
{
    size_t i = (size_t)blockIdx.x * 256 + threadIdx.x;   // over 4096*1024 chunk
    size_t gi = (size_t)row0 * HD + i;
    int row = row0 + (int)(i >> 10);
    float g = gate[row];
    out[gi] = g * localc[i] + (1.f - g) * out[gi];
}

__global__ __launch_bounds__(1024)
void divloss_k(const float* __restrict__ usage, float* __restrict__ out)
{
    int t = threadIdx.x;
    float u[4];
#pragma unroll
    for (int q = 0; q < 4; ++q) u[q] = usage[t + q * 1024];
    __shared__ float s1[1024];
    s1[t] = u[0] + u[1] + u[2] + u[3];
    __syncthreads();
    for (int o = 512; o > 0; o >>= 1) {
        if (t < o) s1[t] += s1[t + o];
        __syncthreads();
    }
    float inv = 1.0f / (s1[0] + 1e-8f);
    __syncthreads();
    float acc = 0.f;
#pragma unroll
    for (int q = 0; q < 4; ++q) {
        float d = u[q] * inv - (1.0f / 4096.0f);
        acc += d * d;
    }
    s1[t] = acc;
    __syncthreads();
    for (int o = 512; o > 0; o >>= 1) {
        if (t < o) s1[t] += s1[t + o];
        __syncthreads();
    }
    // scale = min(1, B*S*H/(P*K)) = 1
    if (t == 0) out[(size_t)MR * HD] = s1[0] * (1.0f / 4096.0f) * 0.01f;
}

extern "C" void kernel_launch(void* const* d_in, const int* in_sizes, int n_in,
                              void* d_out, int out_size, void* d_ws, size_t ws_size,
                              hipStream_t stream)
{
    const float* x     = (const float*)d_in[0];
    const float* pool  = (const float*)d_in[1];
    const float* w1    = (const float*)d_in[2];
    const float* b1    = (const float*)d_in[3];
    const float* w2    = (const float*)d_in[4];
    const float* b2    = (const float*)d_in[5];
    const float* temp  = (const float*)d_in[6];
    const float* wproj = (const float*)d_in[7];
    const float* bproj = (const float*)d_in[8];
    const float* ln_g  = (const float*)d_in[9];
    const float* ln_b  = (const float*)d_in[10];
    const float* wmap  = (const float*)d_in[11];
    const float* bmap  = (const float*)d_in[12];
    const float* convw = (const float*)d_in[13];
    const float* convb = (const float*)d_in[14];
    const float* wout  = (const float*)d_in[15];
    const float* bout  = (const float*)d_in[16];
    const float* wrp   = (const float*)d_in[17];
    const float* brp   = (const float*)d_in[18];
    const float* wg    = (const float*)d_in[19];
    const float* bg    = (const float*)d_in[20];
    float* out = (float*)d_out;

    float* ws = (float*)d_ws;
    size_t off = 0;
    float* inter    = ws + off; off += (size_t)MR * INTERD;   // 16.78M f
    float* combined = ws + off; off += (size_t)MR * 1024;     // 16.78M f
    float* trans    = ws + off; off += (size_t)MR * DD;       //  8.39M f
    float* concatc  = ws + off; off += (size_t)4096 * 3072;   // 12.58M f (chunk)
    float* localc   = ws + off; off += (size_t)4096 * 1024;   //  4.19M f (chunk)
    float* cand_v   = ws + off; off += (size_t)MR * 128;      //  2.10M f
    int*   cand_i   = (int*)(ws + off); off += (size_t)MR * 128;
    float* gate     = ws + off; off += MR;
    float* usage    = ws + off; off += PD;

    hipMemsetAsync(usage, 0, PD * sizeof(float), stream);

    dim3 blk(256);
    // G1: inter = relu(x @ w1^T + b1)        [16384 x 1024, K=1024]
    gemm_k<0,0,1><<<dim3(16,256), blk, 0, stream>>>(x, HD, 0, w1, HD, b1,
        inter, INTERD, 0, 0, HD, 0, 0, nullptr, nullptr);
    // G2: per-tile top-2 candidates of logits = inter @ w2^T + b2  [K=1024, N=4096]
    gemm_k<0,0,3><<<dim3(64,256), blk, 0, stream>>>(inter, INTERD, 0, w2, INTERD, b2,
        nullptr, 0, 0, 0, INTERD, 0, 0, cand_v, cand_i);
    // merge: global top-2, softmax, usage, weighted_map -> combined[:,512:]
    merge_k<<<dim3(MR), dim3(64), 0, stream>>>(cand_v, cand_i, pool, temp, combined, usage);
    // G3: combined[:, :512] = x @ wproj^T + bproj (raw)
    gemm_k<0,0,0><<<dim3(8,256), blk, 0, stream>>>(x, HD, 0, wproj, HD, bproj,
        combined, 1024, 0, 0, HD, 0, 0, nullptr, nullptr);
    // LN in place on combined[:, :512]
    ln_k<<<dim3(MR), dim3(256), 0, stream>>>(combined, ln_g, ln_b);
    // G4: trans = combined @ wmap^T + bmap   [N=512, K=1024]
    gemm_k<0,0,0><<<dim3(8,256), blk, 0, stream>>>(combined, 1024, 0, wmap, 1024, bmap,
        trans, DD, 0, 0, 1024, 0, 0, nullptr, nullptr);
    // G5: out[:16M] = global_out = trans @ wrp^T + brp   [N=1024, K=512]
    gemm_k<0,0,0><<<dim3(16,256), blk, 0, stream>>>(trans, DD, 0, wrp, DD, brp,
        out, HD, 0, 0, DD, 0, 0, nullptr, nullptr);
    // gate
    gate_k<<<dim3(MR), dim3(256), 0, stream>>>(x, wg, bg, gate);
    // diversity loss (usage complete after merge)
    divloss_k<<<dim3(1), dim3(1024), 0, stream>>>(usage, out);

    // conv branch, chunked over 4x4096 rows
    const int dils[3] = {1, 2, 4};
    for (int ch = 0; ch < 4; ++ch) {
        int row0 = ch * 4096;
        for (int i = 0; i < 3; ++i) {
            gemm_k<1,1,2><<<dim3(16,64), blk, 0, stream>>>(
                x, 0, 0, convw + (size_t)i * HD * HD * 3, 0, convb + (size_t)i * HD,
                concatc, 3072, i * 1024, row0, 3072, row0, dils[i], nullptr, nullptr);
        }
        // local chunk = gelu-concat @ wout^T + bout   [N=1024, K=3072]
        gemm_k<0,0,0><<<dim3(16,64), blk, 0, stream>>>(concatc, 3072, row0, wout, 3072, bout,
            localc, 1024, 0, row0, 3072, row0, 0, nullptr, nullptr);
        combine_k<<<dim3(4096 * 1024 / 256), dim3(256), 0, stream>>>(localc, gate, out, row0);
    }
}

// Round 2
// 3381.060 us; speedup vs baseline: 3.0959x; 3.0959x over previous
//
#include <hip/hip_runtime.h>
#include <math.h>
#include <climits>

#define SQ 4096          // sequence length
#define HD 1024          // hidden
#define PD 4096          // pool size
#define DD 512           // pool dim
#define MR 16384         // B*S rows
#define INTERD 1024
#define SP 4104          // padded sequence rows per batch (4 + 4096 + 4)

typedef __attribute__((ext_vector_type(8))) short short8;
typedef __attribute__((ext_vector_type(4))) float f32x4;

__device__ __forceinline__ unsigned short f2bf(float f) {
    union { float f; unsigned u; } v; v.f = f;
    unsigned r = v.u + 0x7fff + ((v.u >> 16) & 1);
    return (unsigned short)(r >> 16);
}

__device__ __forceinline__ void gll16(const unsigned short* g, unsigned short* l) {
    __builtin_amdgcn_global_load_lds(
        (const __attribute__((address_space(1))) void*)g,
        (__attribute__((address_space(3))) void*)l, 16, 0, 0);
}

// ===========================================================================
// bf16 MFMA GEMM: 128x128 tile, BK=64, 256 threads (4 waves), 16x16x32 mfma.
// C[m,n] = EPI( sum_k A[m,k]*B[n,k] + bias[n] )
// AMODE 0: A bf16 row-major [M, lda]
// AMODE 1: A = xpad gather: m->(b,s), k->(tap,cin); row b*SP + s+4+(tap-1)*dil
// BMODE 0: B bf16 row-major [N, ldb]
// BMODE 1: B = wconvb gather: [tap][n][cin] (base pre-offset for conv i)
// EPI 0: Cf[m*ldc+coff+n] = acc+bias                (fp32 out)
// EPI 1: Cb[m*ldc+coff+n] = bf16(gelu(acc+bias))    (bf16 out)
// EPI 2: Cb[m*ldc+coff+n] = bf16(acc+bias)          (bf16 out)
// EPI 3: o=m*1024+n; Cf[o] = g*(acc+bias) + (1-g)*Cf[o], g=gate[m]
// ===========================================================================
template<int AMODE, int BMODE, int EPI>
__global__ __launch_bounds__(256)
void bgemm_k(const unsigned short* __restrict__ A, int lda,
             const unsigned short* __restrict__ Bm, int ldb,
             const float* __restrict__ bias,
             float* __restrict__ Cf, unsigned short* __restrict__ Cb,
             int ldc, int coff, int K, int dil,
             const float* __restrict__ gate)
{
    __shared__ __align__(16) unsigned short As[128 * 64];
    __shared__ __align__(16) unsigned short Bs[128 * 64];
    const int tid = threadIdx.x;
    const int w = tid >> 6;          // wave 0..3
    const int ln = tid & 63;
    const int bm = blockIdx.y * 128;
    const int bn = blockIdx.x * 128;
    const int wm = (w >> 1) * 64;    // wave m-offset
    const int wn = (w & 1) * 64;     // wave n-offset

    f32x4 acc[4][4] = {};

    const int l8 = (ln & 7) * 8;         // elem offset within 64-wide k-tile
    const int rsub = w * 8 + (ln >> 3);  // staged row for q=0

    for (int kt = 0; kt < K; kt += 64) {
        const int tap = kt >> 10;
        const int cin0 = kt & 1023;
#pragma unroll
        for (int q = 0; q < 4; ++q) {
            const int r = q * 32 + rsub;
            const unsigned short* asrc;
            if (AMODE == 0) {
                asrc = A + (size_t)(bm + r) * lda + kt + l8;
            } else {
                int m = bm + r;
                int b = m >> 12;
                int s = m & (SQ - 1);
                asrc = A + (size_t)(b * SP + s + 4 + (tap - 1) * dil) * 1024 + cin0 + l8;
            }
            gll16(asrc, &As[q * 2048 + w * 512]);
            const unsigned short* bsrc;
            if (BMODE == 0) {
                bsrc = Bm + (size_t)(bn + r) * ldb + kt + l8;
            } else {
                bsrc = Bm + (size_t)(tap * 1024 + bn + r) * 1024 + cin0 + l8;
            }
            gll16(bsrc, &Bs[q * 2048 + w * 512]);
        }
        __syncthreads();
#pragma unroll
        for (int ks = 0; ks < 2; ++ks) {
            const int kb = ks * 32 + (ln >> 4) * 8;
            short8 af[4], bf[4];
#pragma unroll
            for (int i = 0; i < 4; ++i)
                af[i] = *(const short8*)&As[(wm + i * 16 + (ln & 15)) * 64 + kb];
#pragma unroll
            for (int j = 0; j < 4; ++j)
                bf[j] = *(const short8*)&Bs[(wn + j * 16 + (ln & 15)) * 64 + kb];
#pragma unroll
            for (int i = 0; i < 4; ++i)
#pragma unroll
                for (int j = 0; j < 4; ++j)
                    acc[i][j] = __builtin_amdgcn_mfma_f32_16x16x32_bf16(
                        af[i], bf[j], acc[i][j], 0, 0, 0);
        }
        __syncthreads();
    }

    // epilogue: D row = (ln>>4)*4 + r, col = ln&15 within each 16x16 tile
#pragma unroll
    for (int i = 0; i < 4; ++i) {
        const int mrow = bm + wm + i * 16 + (ln >> 4) * 4;
#pragma unroll
        for (int j = 0; j < 4; ++j) {
            const int ncol = bn + wn + j * 16 + (ln & 15);
            const float bs = bias[ncol];
#pragma unroll
            for (int r = 0; r < 4; ++r) {
                const int m = mrow + r;
                float v = acc[i][j][r] + bs;
                if (EPI == 0) {
                    Cf[(size_t)m * ldc + coff + ncol] = v;
                } else if (EPI == 1) {
                    v = 0.5f * v * (1.0f + erff(v * 0.70710678118654752f));
                    Cb[(size_t)m * ldc + coff + ncol] = f2bf(v);
                } else if (EPI == 2) {
                    Cb[(size_t)m * ldc + coff + ncol] = f2bf(v);
                } else {
                    float g = gate[m];
                    size_t o = (size_t)m * 1024 + ncol;
                    Cf[o] = g * v + (1.0f - g) * Cf[o];
                }
            }
        }
    }
}

// ===========================================================================
// fp32 tiled GEMM (router path — index-sensitive, stays fp32)
// ===========================================================================
template<int EPI>   // 1 relu->C, 3 per-row top-2 candidates
__global__ __launch_bounds__(256)
void gemm_k(const float* __restrict__ A, int lda,
            const float* __restrict__ Bm, int ldb,
            const float* __restrict__ bias,
            float* __restrict__ C, int ldc, int K,
            float* __restrict__ cand_v, int* __restrict__ cand_i)
{
    __shared__ float As[16][68];
    __shared__ float Bs[16][68];
    const int tid = threadIdx.x;
    const int tx = tid & 15;
    const int ty = tid >> 4;
    const int bm = blockIdx.y * 64;
    const int bn = blockIdx.x * 64;

    float acc[4][4];
#pragma unroll
    for (int i = 0; i < 4; ++i)
#pragma unroll
        for (int j = 0; j < 4; ++j) acc[i][j] = 0.f;

    for (int kt = 0; kt < K; kt += 16) {
#pragma unroll
        for (int l = 0; l < 4; ++l) {
            int idx = tid + l * 256;
            int r = idx >> 4;
            int c = idx & 15;
            As[c][r] = A[(size_t)(bm + r) * lda + (kt + c)];
            Bs[c][r] = Bm[(size_t)(bn + r) * ldb + (kt + c)];
        }
        __syncthreads();
#pragma unroll
        for (int c = 0; c < 16; ++c) {
            float a[4], b[4];
#pragma unroll
            for (int i = 0; i < 4; ++i) a[i] = As[c][ty * 4 + i];
#pragma unroll
            for (int j = 0; j < 4; ++j) b[j] = Bs[c][tx * 4 + j];
#pragma unroll
            for (int i = 0; i < 4; ++i)
#pragma unroll
                for (int j = 0; j < 4; ++j)
                    acc[i][j] = fmaf(a[i], b[j], acc[i][j]);
        }
        __syncthreads();
    }

    if constexpr (EPI == 3) {
        __shared__ float lv[64][16][2];
        __shared__ int   li[64][16][2];
#pragma unroll
        for (int i = 0; i < 4; ++i) {
            int rl = ty * 4 + i;
            float bv0 = -1e30f, bv1 = -1e30f; int bi0 = INT_MAX, bi1 = INT_MAX;
#pragma unroll
            for (int j = 0; j < 4; ++j) {
                int n = bn + tx * 4 + j;
                float v = acc[i][j] + bias[n];
                if (v > bv0 || (v == bv0 && n < bi0)) { bv1 = bv0; bi1 = bi0; bv0 = v; bi0 = n; }
                else if (v > bv1 || (v == bv1 && n < bi1)) { bv1 = v; bi1 = n; }
            }
            lv[rl][tx][0] = bv0; lv[rl][tx][1] = bv1;
            li[rl][tx][0] = bi0; li[rl][tx][1] = bi1;
        }
        __syncthreads();
        if (tid < 64) {
            float bv0 = -1e30f, bv1 = -1e30f; int bi0 = INT_MAX, bi1 = INT_MAX;
            for (int q = 0; q < 16; ++q) {
#pragma unroll
                for (int u = 0; u < 2; ++u) {
                    float v = lv[tid][q][u]; int n = li[tid][q][u];
                    if (v > bv0 || (v == bv0 && n < bi0)) { bv1 = bv0; bi1 = bi0; bv0 = v; bi0 = n; }
                    else if (v > bv1 || (v == bv1 && n < bi1)) { bv1 = v; bi1 = n; }
                }
            }
            size_t base = (size_t)(bm + tid) * 128 + (size_t)blockIdx.x * 2;
            cand_v[base] = bv0; cand_v[base + 1] = bv1;
            cand_i[base] = bi0; cand_i[base + 1] = bi1;
        }
    } else {
#pragma unroll
        for (int i = 0; i < 4; ++i)
#pragma unroll
            for (int j = 0; j < 4; ++j) {
                int n = bn + tx * 4 + j;
                float v = acc[i][j] + bias[n];
                if (EPI == 1) v = fmaxf(v, 0.f);
                C[(size_t)(bm + ty * 4 + i) * ldc + n] = v;
            }
    }
}

// merge candidates -> top-2, softmax, usage, weighted_map -> combined_b[:,512:]
__global__ __launch_bounds__(64)
void merge_k(const float* __restrict__ cand_v, const int* __restrict__ cand_i,
             const float* __restrict__ pool, const float* __restrict__ tptr,
             unsigned short* __restrict__ combined_b, float* __restrict__ usage)
{
    int row = blockIdx.x;
    int t = threadIdx.x;
    __shared__ float sv[128];
    __shared__ int   si[128];
    sv[t]      = cand_v[(size_t)row * 128 + t];
    sv[t + 64] = cand_v[(size_t)row * 128 + 64 + t];
    si[t]      = cand_i[(size_t)row * 128 + t];
    si[t + 64] = cand_i[(size_t)row * 128 + 64 + t];
    __syncthreads();
    __shared__ float wsh[2];
    __shared__ int   ish[2];
    if (t == 0) {
        float bv0 = -1e30f, bv1 = -1e30f; int bi0 = INT_MAX, bi1 = INT_MAX;
        for (int q = 0; q < 128; ++q) {
            float v = sv[q]; int n = si[q];
            if (v > bv0 || (v == bv0 && n < bi0)) { bv1 = bv0; bi1 = bi0; bv0 = v; bi0 = n; }
            else if (v > bv1 || (v == bv1 && n < bi1)) { bv1 = v; bi1 = n; }
        }
        float tc = fminf(fmaxf(tptr[0], 0.1f), 5.0f);
        float v0 = fminf(fmaxf(bv0 / tc, -10.f), 10.f);
        float v1 = fminf(fmaxf(bv1 / tc, -10.f), 10.f);
        float e1 = expf(v1 - v0);
        float w0 = 1.f / (1.f + e1);
        float w1 = e1 / (1.f + e1);
        atomicAdd(&usage[bi0], w0);
        atomicAdd(&usage[bi1], w1);
        wsh[0] = w0; wsh[1] = w1; ish[0] = bi0; ish[1] = bi1;
    }
    __syncthreads();
    float w0 = wsh[0], w1 = wsh[1];
    const float* p0 = pool + (size_t)ish[0] * DD;
    const float* p1 = pool + (size_t)ish[1] * DD;
    unsigned short* dst = combined_b + (size_t)row * 1024 + 512;
    for (int j = t; j < DD; j += 64) dst[j] = f2bf(w0 * p0[j] + w1 * p1[j]);
}

// layernorm projx fp32 -> combined_b[:, :512] bf16
__global__ __launch_bounds__(256)
void ln_k(const float* __restrict__ projx, unsigned short* __restrict__ combined_b,
          const float* __restrict__ g, const float* __restrict__ b)
{
    int row = blockIdx.x;
    int t = threadIdx.x;
    const float* p = projx + (size_t)row * DD;
    float x0 = p[t], x1 = p[t + 256];
    __shared__ float s1[256], s2[256];
    s1[t] = x0 + x1;
    s2[t] = x0 * x0 + x1 * x1;
    __syncthreads();
    for (int o = 128; o > 0; o >>= 1) {
        if (t < o) { s1[t] += s1[t + o]; s2[t] += s2[t + o]; }
        __syncthreads();
    }
    float mu = s1[0] * (1.0f / 512.0f);
    float var = s2[0] * (1.0f / 512.0f) - mu * mu;
    float inv = rsqrtf(var + 1e-5f);
    unsigned short* dst = combined_b + (size_t)row * 1024;
    dst[t]       = f2bf((x0 - mu) * inv * g[t] + b[t]);
    dst[t + 256] = f2bf((x1 - mu) * inv * g[t + 256] + b[t + 256]);
}

__global__ __launch_bounds__(256)
void gate_k(const float* __restrict__ x, const float* __restrict__ wg,
            const float* __restrict__ bg, float* __restrict__ gate)
{
    int row = blockIdx.x;
    int t = threadIdx.x;
    const float* p = x + (size_t)row * HD;
    float s = p[t] * wg[t] + p[t + 256] * wg[t + 256]
            + p[t + 512] * wg[t + 512] + p[t + 768] * wg[t + 768];
    __shared__ float s1[256];
    s1[t] = s;
    __syncthreads();
    for (int o = 128; o > 0; o >>= 1) {
        if (t < o) s1[t] += s1[t + o];
        __syncthreads();
    }
    if (t == 0) gate[row] = 1.f / (1.f + expf(-(s1[0] + bg[0])));
}

__global__ __launch_bounds__(1024)
void divloss_k(const float* __restrict__ usage, float* __restrict__ out)
{
    int t = threadIdx.x;
    float u[4];
#pragma unroll
    for (int q = 0; q < 4; ++q) u[q] = usage[t + q * 1024];
    __shared__ float s1[1024];
    s1[t] = u[0] + u[1] + u[2] + u[3];
    __syncthreads();
    for (int o = 512; o > 0; o >>= 1) {
        if (t < o) s1[t] += s1[t + o];
        __syncthreads();
    }
    float inv = 1.0f / (s1[0] + 1e-8f);
    __syncthreads();
    float acc = 0.f;
#pragma unroll
    for (int q = 0; q < 4; ++q) {
        float d = u[q] * inv - (1.0f / 4096.0f);
        acc += d * d;
    }
    s1[t] = acc;
    __syncthreads();
    for (int o = 512; o > 0; o >>= 1) {
        if (t < o) s1[t] += s1[t + o];
        __syncthreads();
    }
    if (t == 0) out[(size_t)MR * HD] = s1[0] * (1.0f / 4096.0f) * 0.01f;
}

// ---- conversion kernels ----
__global__ __launch_bounds__(256)
void xpad_k(const float* __restrict__ x, unsigned short* __restrict__ xpad)
{
    size_t idx = (size_t)blockIdx.x * 256 + threadIdx.x;  // over 4*SP*1024
    int c = (int)(idx & 1023);
    int sp = (int)((idx >> 10) % SP);
    int b = (int)(idx / ((size_t)SP * 1024));
    float v = 0.f;
    if (sp >= 4 && sp < SQ + 4)
        v = x[((size_t)b * SQ + sp - 4) * 1024 + c];
    xpad[idx] = f2bf(v);
}

// conv_w [i][o][in][3] -> wconvb [i][tap][o][in]
__global__ __launch_bounds__(256)
void wconv_k(const float* __restrict__ cw, unsigned short* __restrict__ wb)
{
    size_t idx = (size_t)blockIdx.x * 256 + threadIdx.x;  // over 9*1024*1024
    int it = (int)(idx >> 20);       // i*3+tap
    int i = it / 3, tap = it % 3;
    int o = (int)((idx >> 10) & 1023);
    int in = (int)(idx & 1023);
    wb[idx] = f2bf(cw[(((size_t)(i * 1024 + o)) * 1024 + in) * 3 + tap]);
}

__global__ __launch_bounds__(256)
void cvt_k(const float* __restrict__ src, unsigned short* __restrict__ dst, int n)
{
    int idx = blockIdx.x * 256 + threadIdx.x;
    if (idx < n) dst[idx] = f2bf(src[idx]);
}

extern "C" void kernel_launch(void* const* d_in, const int* in_sizes, int n_in,
                              void* d_out, int out_size, void* d_ws, size_t ws_size,
                              hipStream_t stream)
{
    const float* x     = (const float*)d_in[0];
    const float* pool  = (const float*)d_in[1];
    const float* w1    = (const float*)d_in[2];
    const float* b1    = (const float*)d_in[3];
    const float* w2    = (const float*)d_in[4];
    const float* b2    = (const float*)d_in[5];
    const float* temp  = (const float*)d_in[6];
    const float* wproj = (const float*)d_in[7];
    const float* bproj = (const float*)d_in[8];
    const float* ln_g  = (const float*)d_in[9];
    const float* ln_b  = (const float*)d_in[10];
    const float* wmap  = (const float*)d_in[11];
    const float* bmap  = (const float*)d_in[12];
    const float* convw = (const float*)d_in[13];
    const float* convb = (const float*)d_in[14];
    const float* wout  = (const float*)d_in[15];
    const float* bout  = (const float*)d_in[16];
    const float* wrp   = (const float*)d_in[17];
    const float* brp   = (const float*)d_in[18];
    const float* wg    = (const float*)d_in[19];
    const float* bg    = (const float*)d_in[20];
    float* out = (float*)d_out;

    char* w8 = (char*)d_ws;
    float*          inter      = (float*)(w8 + 0);                  // 67.1 MB [G1..G2]
    unsigned short* concat     = (unsigned short*)(w8 + 0);         // 100.7 MB, aliases inter (conv phase)
    float*          projx      = (float*)(w8 + 100663296);          // 33.6 MB
    unsigned short* combined_b = (unsigned short*)(w8 + 134217728); // 33.6 MB
    unsigned short* trans_b    = (unsigned short*)(w8 + 167772160); // 16.8 MB
    float*          cand_v     = (float*)(w8 + 184549376);          // 8.4 MB  [until merge]
    int*            cand_i     = (int*)(w8 + 192937984);            // 8.4 MB  [until merge]
    unsigned short* xpad       = (unsigned short*)(w8 + 184549376); // 33.6 MB, aliases cand
    unsigned short* wconvb     = (unsigned short*)(w8 + 218169344); // 18.9 MB
    unsigned short* woutb      = (unsigned short*)(w8 + 237043712); // 6.3 MB
    unsigned short* wmapb      = (unsigned short*)(w8 + 243335168); // 1.0 MB
    unsigned short* wrpb       = (unsigned short*)(w8 + 244383744); // 1.0 MB
    unsigned short* wprojb     = (unsigned short*)(w8 + 245432320); // 1.0 MB
    float*          gate       = (float*)(w8 + 246480896);          // 64 KB
    float*          usage      = (float*)(w8 + 246546432);          // 16 KB

    hipMemsetAsync(usage, 0, PD * sizeof(float), stream);

    dim3 blk(256);
    // --- router (fp32, index-sensitive) ---
    gemm_k<1><<<dim3(16, 256), blk, 0, stream>>>(x, HD, w1, HD, b1,
        inter, INTERD, HD, nullptr, nullptr);
    gemm_k<3><<<dim3(64, 256), blk, 0, stream>>>(inter, INTERD, w2, INTERD, b2,
        nullptr, 0, INTERD, cand_v, cand_i);
    merge_k<<<dim3(MR), dim3(64), 0, stream>>>(cand_v, cand_i, pool, temp,
        combined_b, usage);

    // --- conversions (cand region dead now; xpad may alias it) ---
    xpad_k<<<dim3((4 * SP * 1024) / 256), blk, 0, stream>>>(x, xpad);
    wconv_k<<<dim3((9 * 1024 * 1024) / 256), blk, 0, stream>>>(convw, wconvb);
    cvt_k<<<dim3((1024 * 3072 + 255) / 256), blk, 0, stream>>>(wout, woutb, 1024 * 3072);
    cvt_k<<<dim3((512 * 1024 + 255) / 256), blk, 0, stream>>>(wmap, wmapb, 512 * 1024);
    cvt_k<<<dim3((1024 * 512 + 255) / 256), blk, 0, stream>>>(wrp, wrpb, 1024 * 512);
    cvt_k<<<dim3((512 * 1024 + 255) / 256), blk, 0, stream>>>(wproj, wprojb, 512 * 1024);

    // --- global branch (bf16 MFMA, not index-sensitive) ---
    // G3: projx = x @ wproj^T + bproj   (AMODE 1 with dil=0 reads xpad unshifted)
    bgemm_k<1, 0, 0><<<dim3(4, 128), blk, 0, stream>>>(xpad, 0, wprojb, HD, bproj,
        projx, nullptr, DD, 0, HD, 0, nullptr);
    ln_k<<<dim3(MR), dim3(256), 0, stream>>>(projx, combined_b, ln_g, ln_b);
    // G4: trans_b = combined_b @ wmap^T + bmap  (bf16 out)
    bgemm_k<0, 0, 2><<<dim3(4, 128), blk, 0, stream>>>(combined_b, 1024, wmapb, 1024,
        bmap, nullptr, trans_b, DD, 0, 1024, 0, nullptr);
    // G5: out = trans_b @ wrp^T + brp  (fp32 global_out)
    bgemm_k<0, 0, 0><<<dim3(8, 128), blk, 0, stream>>>(trans_b, DD, wrpb, DD, brp,
        out, nullptr, HD, 0, DD, 0, nullptr);
    gate_k<<<dim3(MR), dim3(256), 0, stream>>>(x, wg, bg, gate);
    divloss_k<<<dim3(1), dim3(1024), 0, stream>>>(usage, out);

    // --- local branch (bf16 MFMA) ---
    const int dils[3] = {1, 2, 4};
    for (int i = 0; i < 3; ++i) {
        bgemm_k<1, 1, 1><<<dim3(8, 128), blk, 0, stream>>>(
            xpad, 0, wconvb + (size_t)i * 3 * 1024 * 1024, 0,
            convb + (size_t)i * HD,
            nullptr, concat, 3072, i * 1024, 3072, dils[i], nullptr);
    }
    // wout GEMM with fused gate-combine: out = g*local + (1-g)*out
    bgemm_k<0, 0, 3><<<dim3(8, 128), blk, 0, stream>>>(concat, 3072, woutb, 3072,
        bout, out, nullptr, HD, 0, 3072, 0, gate);
}

// Round 3
// 1972.519 us; speedup vs baseline: 5.3066x; 1.7141x over previous
//
#include <hip/hip_runtime.h>
#include <math.h>
#include <climits>

#define SQ 4096          // sequence length
#define HD 1024          // hidden
#define PD 4096          // pool size
#define DD 512           // pool dim
#define MR 16384         // B*S rows
#define INTERD 1024
#define SP 4104          // padded sequence rows per batch (4 + 4096 + 4)
#define NCAND 6          // rescored candidates per row

typedef __attribute__((ext_vector_type(8))) short short8;
typedef __attribute__((ext_vector_type(4))) float f32x4;

__device__ __forceinline__ unsigned short f2bf(float f) {
    union { float f; unsigned u; } v; v.f = f;
    unsigned r = v.u + 0x7fff + ((v.u >> 16) & 1);
    return (unsigned short)(r >> 16);
}

__device__ __forceinline__ void gll16(const unsigned short* g, unsigned short* l) {
    __builtin_amdgcn_global_load_lds(
        (const __attribute__((address_space(1))) void*)g,
        (__attribute__((address_space(3))) void*)l, 16, 0, 0);
}

// ===========================================================================
// bf16 MFMA GEMM: 128x128 tile, BK=64, 256 threads (4 waves), 16x16x32 mfma.
// C[m,n] = EPI( sum_k A[m,k]*B[n,k] + bias[n] )
// AMODE 0: A bf16 row-major [M, lda]
// AMODE 1: A = xpad gather: m->(b,s), k->(tap,cin); row b*SP + s+4+(tap-1)*dil
// BMODE 0: B bf16 row-major [N, ldb]
// BMODE 1: B = wconvb gather: [tap][n][cin] (base pre-offset for conv i)
// EPI 0: Cf[m*ldc+coff+n] = acc+bias                (fp32 out)
// EPI 1: Cb[m*ldc+coff+n] = bf16(gelu(acc+bias))    (bf16 out)
// EPI 2: Cb[m*ldc+coff+n] = bf16(acc+bias)          (bf16 out)
// EPI 3: o=m*1024+n; Cf[o] = g*(acc+bias) + (1-g)*Cf[o], g=gate[m]
// EPI 4: per-row top-2 per 64-col wave-group -> cand_v/cand_i [row][128]
// ===========================================================================
template<int AMODE, int BMODE, int EPI>
__global__ __launch_bounds__(256)
void bgemm_k(const unsigned short* __restrict__ A, int lda,
             const unsigned short* __restrict__ Bm, int ldb,
             const float* __restrict__ bias,
             float* __restrict__ Cf, unsigned short* __restrict__ Cb,
             int ldc, int coff, int K, int dil,
             const float* __restrict__ gate,
             float* __restrict__ cand_v, int* __restrict__ cand_i)
{
    __shared__ __align__(16) unsigned short As[128 * 64];
    __shared__ __align__(16) unsigned short Bs[128 * 64];
    const int tid = threadIdx.x;
    const int w = tid >> 6;          // wave 0..3
    const int ln = tid & 63;
    const int bm = blockIdx.y * 128;
    const int bn = blockIdx.x * 128;
    const int wm = (w >> 1) * 64;    // wave m-offset
    const int wn = (w & 1) * 64;     // wave n-offset

    f32x4 acc[4][4] = {};

    const int l8 = (ln & 7) * 8;         // elem offset within 64-wide k-tile
    const int rsub = w * 8 + (ln >> 3);  // staged row for q=0

    for (int kt = 0; kt < K; kt += 64) {
        const int tap = kt >> 10;
        const int cin0 = kt & 1023;
#pragma unroll
        for (int q = 0; q < 4; ++q) {
            const int r = q * 32 + rsub;
            const unsigned short* asrc;
            if (AMODE == 0) {
                asrc = A + (size_t)(bm + r) * lda + kt + l8;
            } else {
                int m = bm + r;
                int b = m >> 12;
                int s = m & (SQ - 1);
                asrc = A + (size_t)(b * SP + s + 4 + (tap - 1) * dil) * 1024 + cin0 + l8;
            }
            gll16(asrc, &As[q * 2048 + w * 512]);
            const unsigned short* bsrc;
            if (BMODE == 0) {
                bsrc = Bm + (size_t)(bn + r) * ldb + kt + l8;
            } else {
                bsrc = Bm + (size_t)(tap * 1024 + bn + r) * 1024 + cin0 + l8;
            }
            gll16(bsrc, &Bs[q * 2048 + w * 512]);
        }
        __syncthreads();
#pragma unroll
        for (int ks = 0; ks < 2; ++ks) {
            const int kb = ks * 32 + (ln >> 4) * 8;
            short8 af[4], bf[4];
#pragma unroll
            for (int i = 0; i < 4; ++i)
                af[i] = *(const short8*)&As[(wm + i * 16 + (ln & 15)) * 64 + kb];
#pragma unroll
            for (int j = 0; j < 4; ++j)
                bf[j] = *(const short8*)&Bs[(wn + j * 16 + (ln & 15)) * 64 + kb];
#pragma unroll
            for (int i = 0; i < 4; ++i)
#pragma unroll
                for (int j = 0; j < 4; ++j)
                    acc[i][j] = __builtin_amdgcn_mfma_f32_16x16x32_bf16(
                        af[i], bf[j], acc[i][j], 0, 0, 0);
        }
        __syncthreads();
    }

    if constexpr (EPI == 4) {
        // top-2 per row within this wave's 64 cols, ranked (v desc, idx asc)
        const int g = blockIdx.x * 2 + (w & 1);   // col-group 0..63
#pragma unroll
        for (int i = 0; i < 4; ++i) {
#pragma unroll
            for (int r = 0; r < 4; ++r) {
                float v0 = -1e30f, v1 = -1e30f; int i0 = INT_MAX, i1 = INT_MAX;
#pragma unroll
                for (int j = 0; j < 4; ++j) {
                    const int col = bn + wn + j * 16 + (ln & 15);
                    float v = acc[i][j][r] + bias[col];
                    if (v > v0 || (v == v0 && col < i0)) { v1 = v0; i1 = i0; v0 = v; i0 = col; }
                    else if (v > v1 || (v == v1 && col < i1)) { v1 = v; i1 = col; }
                }
#pragma unroll
                for (int msk = 1; msk <= 8; msk <<= 1) {
                    float ov0 = __shfl_xor(v0, msk); int oi0 = __shfl_xor(i0, msk);
                    float ov1 = __shfl_xor(v1, msk); int oi1 = __shfl_xor(i1, msk);
                    if (ov0 > v0 || (ov0 == v0 && oi0 < i0)) {
                        if (v0 > ov1 || (v0 == ov1 && i0 < oi1)) { v1 = v0; i1 = i0; }
                        else { v1 = ov1; i1 = oi1; }
                        v0 = ov0; i0 = oi0;
                    } else {
                        if (ov0 > v1 || (ov0 == v1 && oi0 < i1)) { v1 = ov0; i1 = oi0; }
                    }
                }
                if ((ln & 15) == 0) {
                    const int row = bm + wm + i * 16 + (ln >> 4) * 4 + r;
                    size_t base = (size_t)row * 128 + g * 2;
                    cand_v[base] = v0; cand_v[base + 1] = v1;
                    cand_i[base] = i0; cand_i[base + 1] = i1;
                }
            }
        }
        return;
    }

    // epilogue: D row = (ln>>4)*4 + r, col = ln&15 within each 16x16 tile
#pragma unroll
    for (int i = 0; i < 4; ++i) {
        const int mrow = bm + wm + i * 16 + (ln >> 4) * 4;
#pragma unroll
        for (int j = 0; j < 4; ++j) {
            const int ncol = bn + wn + j * 16 + (ln & 15);
            const float bs = bias[ncol];
#pragma unroll
            for (int r = 0; r < 4; ++r) {
                const int m = mrow + r;
                float v = acc[i][j][r] + bs;
                if (EPI == 0) {
                    Cf[(size_t)m * ldc + coff + ncol] = v;
                } else if (EPI == 1) {
                    v = 0.5f * v * (1.0f + erff(v * 0.70710678118654752f));
                    Cb[(size_t)m * ldc + coff + ncol] = f2bf(v);
                } else if (EPI == 2) {
                    Cb[(size_t)m * ldc + coff + ncol] = f2bf(v);
                } else if (EPI == 3) {
                    float g = gate[m];
                    size_t o = (size_t)m * 1024 + ncol;
                    Cf[o] = g * v + (1.0f - g) * Cf[o];
                }
            }
        }
    }
}

// ===========================================================================
// fp32 G1: inter = relu(x @ w1^T + b1), dual-write fp32 + bf16.
// 64x64 tile, BK=16. M=16384, N=K=1024 hardcoded strides.
// ===========================================================================
__global__ __launch_bounds__(256)
void gemm_relu_k(const float* __restrict__ A, const float* __restrict__ Bm,
                 const float* __restrict__ bias,
                 float* __restrict__ C, unsigned short* __restrict__ Cb)
{
    __shared__ float As[16][68];
    __shared__ float Bs[16][68];
    const int tid = threadIdx.x;
    const int tx = tid & 15;
    const int ty = tid >> 4;
    const int bm = blockIdx.y * 64;
    const int bn = blockIdx.x * 64;

    float acc[4][4];
#pragma unroll
    for (int i = 0; i < 4; ++i)
#pragma unroll
        for (int j = 0; j < 4; ++j) acc[i][j] = 0.f;

    for (int kt = 0; kt < HD; kt += 16) {
#pragma unroll
        for (int l = 0; l < 4; ++l) {
            int idx = tid + l * 256;
            int r = idx >> 4;
            int c = idx & 15;
            As[c][r] = A[(size_t)(bm + r) * HD + (kt + c)];
            Bs[c][r] = Bm[(size_t)(bn + r) * HD + (kt + c)];
        }
        __syncthreads();
#pragma unroll
        for (int c = 0; c < 16; ++c) {
            float a[4], b[4];
#pragma unroll
            for (int i = 0; i < 4; ++i) a[i] = As[c][ty * 4 + i];
#pragma unroll
            for (int j = 0; j < 4; ++j) b[j] = Bs[c][tx * 4 + j];
#pragma unroll
            for (int i = 0; i < 4; ++i)
#pragma unroll
                for (int j = 0; j < 4; ++j)
                    acc[i][j] = fmaf(a[i], b[j], acc[i][j]);
        }
        __syncthreads();
    }
#pragma unroll
    for (int i = 0; i < 4; ++i)
#pragma unroll
        for (int j = 0; j < 4; ++j) {
            int n = bn + tx * 4 + j;
            size_t o = (size_t)(bm + ty * 4 + i) * INTERD + n;
            float v = fmaxf(acc[i][j] + bias[n], 0.f);
            C[o] = v;
            Cb[o] = f2bf(v);
        }
}

// ===========================================================================
// rescore: per row, top-6 of 128 bf16 candidates -> exact fp32 logits ->
// reference-exact top-2 / softmax / usage / weighted_map (bf16 out).
// ===========================================================================
__global__ __launch_bounds__(128)
void rescore_k(const float* __restrict__ cand_v, const int* __restrict__ cand_i,
               const float* __restrict__ inter, const float* __restrict__ w2,
               const float* __restrict__ b2, const float* __restrict__ tptr,
               const float* __restrict__ pool,
               unsigned short* __restrict__ combined_b, float* __restrict__ usage)
{
    const int row = blockIdx.x;
    const int t = threadIdx.x;
    __shared__ float xs[1024];
    __shared__ float cv[128];
    __shared__ int   ci[128];
    __shared__ float rv[128];
    __shared__ int   rp[128];
    __shared__ int   ssel[NCAND];
    __shared__ float ssc[NCAND];
    __shared__ float wsh[2];
    __shared__ int   ish[2];

    const float* irow = inter + (size_t)row * INTERD;
#pragma unroll
    for (int q = 0; q < 8; ++q) xs[t + q * 128] = irow[t + q * 128];
    cv[t] = cand_v[(size_t)row * 128 + t];
    ci[t] = cand_i[(size_t)row * 128 + t];
    __syncthreads();

    // iterative argmax x NCAND (v desc, idx asc)
    for (int j = 0; j < NCAND; ++j) {
        rv[t] = cv[t]; rp[t] = t;
        __syncthreads();
        for (int o = 64; o > 0; o >>= 1) {
            if (t < o) {
                float va = rv[t], vb = rv[t + o];
                int pa = rp[t], pb = rp[t + o];
                if (vb > va || (vb == va && ci[pb] < ci[pa])) { rv[t] = vb; rp[t] = pb; }
            }
            __syncthreads();
        }
        if (t == 0) { int p = rp[0]; ssel[j] = ci[p]; cv[p] = -1e30f; }
        __syncthreads();
    }

    // exact fp32 rescore of the NCAND candidates
    for (int j = 0; j < NCAND; ++j) {
        const float* wr = w2 + (size_t)ssel[j] * INTERD;
        float p = 0.f;
#pragma unroll
        for (int k = t; k < 1024; k += 128) p = fmaf(xs[k], wr[k], p);
        rv[t] = p;
        __syncthreads();
        for (int o = 64; o > 0; o >>= 1) {
            if (t < o) rv[t] += rv[t + o];
            __syncthreads();
        }
        if (t == 0) ssc[j] = rv[0] + b2[ssel[j]];
        __syncthreads();
    }

    if (t == 0) {
        float tc = fminf(fmaxf(tptr[0], 0.1f), 5.0f);
        float bv0 = -1e30f, bv1 = -1e30f; int bi0 = INT_MAX, bi1 = INT_MAX;
        for (int j = 0; j < NCAND; ++j) {
            float v = fminf(fmaxf(ssc[j] / tc, -10.f), 10.f);
            int n = ssel[j];
            if (v > bv0 || (v == bv0 && n < bi0)) { bv1 = bv0; bi1 = bi0; bv0 = v; bi0 = n; }
            else if (v > bv1 || (v == bv1 && n < bi1)) { bv1 = v; bi1 = n; }
        }
        float e1 = expf(bv1 - bv0);
        float w0 = 1.f / (1.f + e1);
        float w1 = e1 / (1.f + e1);
        atomicAdd(&usage[bi0], w0);
        atomicAdd(&usage[bi1], w1);
        wsh[0] = w0; wsh[1] = w1; ish[0] = bi0; ish[1] = bi1;
    }
    __syncthreads();
    float w0 = wsh[0], w1 = wsh[1];
    const float* p0 = pool + (size_t)ish[0] * DD;
    const float* p1 = pool + (size_t)ish[1] * DD;
    unsigned short* dst = combined_b + (size_t)row * 1024 + 512;
#pragma unroll
    for (int q = 0; q < 4; ++q) {
        int j = t + q * 128;
        dst[j] = f2bf(w0 * p0[j] + w1 * p1[j]);
    }
}

// layernorm projx fp32 -> combined_b[:, :512] bf16
__global__ __launch_bounds__(256)
void ln_k(const float* __restrict__ projx, unsigned short* __restrict__ combined_b,
          const float* __restrict__ g, const float* __restrict__ b)
{
    int row = blockIdx.x;
    int t = threadIdx.x;
    const float* p = projx + (size_t)row * DD;
    float x0 = p[t], x1 = p[t + 256];
    __shared__ float s1[256], s2[256];
    s1[t] = x0 + x1;
    s2[t] = x0 * x0 + x1 * x1;
    __syncthreads();
    for (int o = 128; o > 0; o >>= 1) {
        if (t < o) { s1[t] += s1[t + o]; s2[t] += s2[t + o]; }
        __syncthreads();
    }
    float mu = s1[0] * (1.0f / 512.0f);
    float var = s2[0] * (1.0f / 512.0f) - mu * mu;
    float inv = rsqrtf(var + 1e-5f);
    unsigned short* dst = combined_b + (size_t)row * 1024;
    dst[t]       = f2bf((x0 - mu) * inv * g[t] + b[t]);
    dst[t + 256] = f2bf((x1 - mu) * inv * g[t + 256] + b[t + 256]);
}

__global__ __launch_bounds__(256)
void gate_k(const float* __restrict__ x, const float* __restrict__ wg,
            const float* __restrict__ bg, float* __restrict__ gate)
{
    int row = blockIdx.x;
    int t = threadIdx.x;
    const float* p = x + (size_t)row * HD;
    float s = p[t] * wg[t] + p[t + 256] * wg[t + 256]
            + p[t + 512] * wg[t + 512] + p[t + 768] * wg[t + 768];
    __shared__ float s1[256];
    s1[t] = s;
    __syncthreads();
    for (int o = 128; o > 0; o >>= 1) {
        if (t < o) s1[t] += s1[t + o];
        __syncthreads();
    }
    if (t == 0) gate[row] = 1.f / (1.f + expf(-(s1[0] + bg[0])));
}

__global__ __launch_bounds__(1024)
void divloss_k(const float* __restrict__ usage, float* __restrict__ out)
{
    int t = threadIdx.x;
    float u[4];
#pragma unroll
    for (int q = 0; q < 4; ++q) u[q] = usage[t + q * 1024];
    __shared__ float s1[1024];
    s1[t] = u[0] + u[1] + u[2] + u[3];
    __syncthreads();
    for (int o = 512; o > 0; o >>= 1) {
        if (t < o) s1[t] += s1[t + o];
        __syncthreads();
    }
    float inv = 1.0f / (s1[0] + 1e-8f);
    __syncthreads();
    float acc = 0.f;
#pragma unroll
    for (int q = 0; q < 4; ++q) {
        float d = u[q] * inv - (1.0f / 4096.0f);
        acc += d * d;
    }
    s1[t] = acc;
    __syncthreads();
    for (int o = 512; o > 0; o >>= 1) {
        if (t < o) s1[t] += s1[t + o];
        __syncthreads();
    }
    if (t == 0) out[(size_t)MR * HD] = s1[0] * (1.0f / 4096.0f) * 0.01f;
}

// ---- conversion kernels ----
__global__ __launch_bounds__(256)
void xpad_k(const float* __restrict__ x, unsigned short* __restrict__ xpad)
{
    size_t idx = (size_t)blockIdx.x * 256 + threadIdx.x;  // over 4*SP*1024
    int c = (int)(idx & 1023);
    int sp = (int)((idx >> 10) % SP);
    int b = (int)(idx / ((size_t)SP * 1024));
    float v = 0.f;
    if (sp >= 4 && sp < SQ + 4)
        v = x[((size_t)b * SQ + sp - 4) * 1024 + c];
    xpad[idx] = f2bf(v);
}

// conv_w [i][o][in][3] -> wconvb [i][tap][o][in]
__global__ __launch_bounds__(256)
void wconv_k(const float* __restrict__ cw, unsigned short* __restrict__ wb)
{
    size_t idx = (size_t)blockIdx.x * 256 + threadIdx.x;  // over 9*1024*1024
    int it = (int)(idx >> 20);       // i*3+tap
    int i = it / 3, tap = it % 3;
    int o = (int)((idx >> 10) & 1023);
    int in = (int)(idx & 1023);
    wb[idx] = f2bf(cw[(((size_t)(i * 1024 + o)) * 1024 + in) * 3 + tap]);
}

__global__ __launch_bounds__(256)
void cvt_k(const float* __restrict__ src, unsigned short* __restrict__ dst, int n)
{
    int idx = blockIdx.x * 256 + threadIdx.x;
    if (idx < n) dst[idx] = f2bf(src[idx]);
}

extern "C" void kernel_launch(void* const* d_in, const int* in_sizes, int n_in,
                              void* d_out, int out_size, void* d_ws, size_t ws_size,
                              hipStream_t stream)
{
    const float* x     = (const float*)d_in[0];
    const float* pool  = (const float*)d_in[1];
    const float* w1    = (const float*)d_in[2];
    const float* b1    = (const float*)d_in[3];
    const float* w2    = (const float*)d_in[4];
    const float* b2    = (const float*)d_in[5];
    const float* temp  = (const float*)d_in[6];
    const float* wproj = (const float*)d_in[7];
    const float* bproj = (const float*)d_in[8];
    const float* ln_g  = (const float*)d_in[9];
    const float* ln_b  = (const float*)d_in[10];
    const float* wmap  = (const float*)d_in[11];
    const float* bmap  = (const float*)d_in[12];
    const float* convw = (const float*)d_in[13];
    const float* convb = (const float*)d_in[14];
    const float* wout  = (const float*)d_in[15];
    const float* bout  = (const float*)d_in[16];
    const float* wrp   = (const float*)d_in[17];
    const float* brp   = (const float*)d_in[18];
    const float* wg    = (const float*)d_in[19];
    const float* bg    = (const float*)d_in[20];
    float* out = (float*)d_out;

    char* w8 = (char*)d_ws;
    float*          inter      = (float*)(w8 + 0);                  // 67.1 MB fp32 [until rescore]
    unsigned short* inter_b    = (unsigned short*)(w8 + 67108864);  // 33.6 MB bf16 [until G2cand done]
    unsigned short* concat     = (unsigned short*)(w8 + 0);         // 100.7 MB, aliases inter+inter_b (conv phase)
    float*          projx      = (float*)(w8 + 100663296);          // 33.6 MB
    unsigned short* combined_b = (unsigned short*)(w8 + 134217728); // 33.6 MB
    unsigned short* trans_b    = (unsigned short*)(w8 + 167772160); // 16.8 MB
    float*          cand_v     = (float*)(w8 + 184549376);          // 8.4 MB  [until rescore]
    int*            cand_i     = (int*)(w8 + 192937984);            // 8.4 MB  [until rescore]
    unsigned short* xpad       = (unsigned short*)(w8 + 184549376); // 33.6 MB, aliases cand (after rescore)
    unsigned short* wconvb     = (unsigned short*)(w8 + 218169344); // 18.9 MB
    unsigned short* woutb      = (unsigned short*)(w8 + 237043712); // 6.3 MB
    unsigned short* w2b        = (unsigned short*)(w8 + 237043712); // 8.4 MB, aliases wout/wmap/wrp slots (early)
    unsigned short* wmapb      = (unsigned short*)(w8 + 243335168); // 1.0 MB
    unsigned short* wrpb       = (unsigned short*)(w8 + 244383744); // 1.0 MB
    unsigned short* wprojb     = (unsigned short*)(w8 + 245432320); // 1.0 MB
    float*          gate       = (float*)(w8 + 246480896);          // 64 KB
    float*          usage      = (float*)(w8 + 246546432);          // 16 KB

    hipMemsetAsync(usage, 0, PD * sizeof(float), stream);

    dim3 blk(256);
    // --- router ---
    // G1: inter = relu(x@w1^T+b1), fp32 + bf16
    gemm_relu_k<<<dim3(16, 256), blk, 0, stream>>>(x, w1, b1, inter, inter_b);
    // w2 -> bf16 (region reused by wout/wmap/wrp later)
    cvt_k<<<dim3((PD * INTERD + 255) / 256), blk, 0, stream>>>(w2, w2b, PD * INTERD);
    // G2cand: bf16 MFMA logits, top-2 per 64-col group
    bgemm_k<0, 0, 4><<<dim3(32, 128), blk, 0, stream>>>(inter_b, INTERD, w2b, INTERD,
        b2, nullptr, nullptr, 0, 0, INTERD, 0, nullptr, cand_v, cand_i);
    // exact fp32 rescore + selection + weighted_map + usage
    rescore_k<<<dim3(MR), dim3(128), 0, stream>>>(cand_v, cand_i, inter, w2, b2,
        temp, pool, combined_b, usage);

    // --- conversions (cand + inter regions dead; aliases safe) ---
    xpad_k<<<dim3((4 * SP * 1024) / 256), blk, 0, stream>>>(x, xpad);
    wconv_k<<<dim3((9 * 1024 * 1024) / 256), blk, 0, stream>>>(convw, wconvb);
    cvt_k<<<dim3((1024 * 3072 + 255) / 256), blk, 0, stream>>>(wout, woutb, 1024 * 3072);
    cvt_k<<<dim3((512 * 1024 + 255) / 256), blk, 0, stream>>>(wmap, wmapb, 512 * 1024);
    cvt_k<<<dim3((1024 * 512 + 255) / 256), blk, 0, stream>>>(wrp, wrpb, 1024 * 512);
    cvt_k<<<dim3((512 * 1024 + 255) / 256), blk, 0, stream>>>(wproj, wprojb, 512 * 1024);

    // --- global branch (bf16 MFMA) ---
    bgemm_k<1, 0, 0><<<dim3(4, 128), blk, 0, stream>>>(xpad, 0, wprojb, HD, bproj,
        projx, nullptr, DD, 0, HD, 0, nullptr, nullptr, nullptr);
    ln_k<<<dim3(MR), dim3(256), 0, stream>>>(projx, combined_b, ln_g, ln_b);
    bgemm_k<0, 0, 2><<<dim3(4, 128), blk, 0, stream>>>(combined_b, 1024, wmapb, 1024,
        bmap, nullptr, trans_b, DD, 0, 1024, 0, nullptr, nullptr, nullptr);
    bgemm_k<0, 0, 0><<<dim3(8, 128), blk, 0, stream>>>(trans_b, DD, wrpb, DD, brp,
        out, nullptr, HD, 0, DD, 0, nullptr, nullptr, nullptr);
    gate_k<<<dim3(MR), dim3(256), 0, stream>>>(x, wg, bg, gate);
    divloss_k<<<dim3(1), dim3(1024), 0, stream>>>(usage, out);

    // --- local branch (bf16 MFMA) ---
    const int dils[3] = {1, 2, 4};
    for (int i = 0; i < 3; ++i) {
        bgemm_k<1, 1, 1><<<dim3(8, 128), blk, 0, stream>>>(
            xpad, 0, wconvb + (size_t)i * 3 * 1024 * 1024, 0,
            convb + (size_t)i * HD,
            nullptr, concat, 3072, i * 1024, 3072, dils[i], nullptr, nullptr, nullptr);
    }
    // wout GEMM with fused gate-combine: out = g*local + (1-g)*out
    bgemm_k<0, 0, 3><<<dim3(8, 128), blk, 0, stream>>>(concat, 3072, woutb, 3072,
        bout, out, nullptr, HD, 0, 3072, 0, gate, nullptr, nullptr);
}

// Round 4
// 1871.905 us; speedup vs baseline: 5.5918x; 1.0537x over previous
//
#include <hip/hip_runtime.h>
#include <math.h>
#include <climits>

#define SQ 4096          // sequence length
#define HD 1024          // hidden
#define PD 4096          // pool size
#define DD 512           // pool dim
#define MR 16384         // B*S rows
#define INTERD 1024
#define SP 4104          // padded sequence rows per batch (4 + 4096 + 4)
#define NCAND 6          // rescored candidates per row

typedef __attribute__((ext_vector_type(8))) short short8;
typedef __attribute__((ext_vector_type(4))) float f32x4;

__device__ __forceinline__ unsigned short f2bf(float f) {
    union { float f; unsigned u; } v; v.f = f;
    unsigned r = v.u + 0x7fff + ((v.u >> 16) & 1);
    return (unsigned short)(r >> 16);
}

__device__ __forceinline__ void gll16(const unsigned short* g, unsigned short* l) {
    __builtin_amdgcn_global_load_lds(
        (const __attribute__((address_space(1))) void*)g,
        (__attribute__((address_space(3))) void*)l, 16, 0, 0);
}

// fast tanh-GELU (max dev from erf-GELU ~3e-4; outputs stored bf16 anyway)
__device__ __forceinline__ float gelu_f(float v) {
    float u = v * (0.7978845608028654f + 0.03567740813636141f * v * v);
    float e = __expf(2.0f * u);
    float th = 1.0f - 2.0f / (e + 1.0f);
    return 0.5f * v * (1.0f + th);
}

// ===========================================================================
// bf16 MFMA GEMM: 128x128 tile, BK=64, 256 threads (4 waves), 16x16x32 mfma.
// C[m,n] = EPI( sum_k A[m,k]*B[n,k] + bias[n] )
// AMODE 0: A bf16 row-major [M, lda]
// AMODE 1: A = xpad gather: m->(b,s), k->(tap,cin); row b*SP + s+4+(tap-1)*dil
// BMODE 0: B bf16 row-major [N, ldb]
// BMODE 1: B = wconvb gather: [tap][n][cin] (base pre-offset for conv i)
// EPI 0: Cf = acc+bias (fp32) | 1: bf16(gelu) | 2: bf16 | 3: gate-combine
// EPI 4: per-row top-2 per 64-col wave-group -> cand_v/cand_i [row][128]
// ===========================================================================
template<int AMODE, int BMODE, int EPI>
__global__ __launch_bounds__(256)
void bgemm_k(const unsigned short* __restrict__ A, int lda,
             const unsigned short* __restrict__ Bm, int ldb,
             const float* __restrict__ bias,
             float* __restrict__ Cf, unsigned short* __restrict__ Cb,
             int ldc, int coff, int K, int dil,
             const float* __restrict__ gate,
             float* __restrict__ cand_v, int* __restrict__ cand_i)
{
    __shared__ __align__(16) unsigned short As[128 * 64];
    __shared__ __align__(16) unsigned short Bs[128 * 64];
    const int tid = threadIdx.x;
    const int w = tid >> 6;          // wave 0..3
    const int ln = tid & 63;
    const int bm = blockIdx.y * 128;
    const int bn = blockIdx.x * 128;
    const int wm = (w >> 1) * 64;    // wave m-offset
    const int wn = (w & 1) * 64;     // wave n-offset

    f32x4 acc[4][4] = {};

    const int l8 = (ln & 7) * 8;         // elem offset within 64-wide k-tile
    const int rsub = w * 8 + (ln >> 3);  // staged row for q=0

    for (int kt = 0; kt < K; kt += 64) {
        const int tap = kt >> 10;
        const int cin0 = kt & 1023;
#pragma unroll
        for (int q = 0; q < 4; ++q) {
            const int r = q * 32 + rsub;
            const unsigned short* asrc;
            if (AMODE == 0) {
                asrc = A + (size_t)(bm + r) * lda + kt + l8;
            } else {
                int m = bm + r;
                int b = m >> 12;
                int s = m & (SQ - 1);
                asrc = A + (size_t)(b * SP + s + 4 + (tap - 1) * dil) * 1024 + cin0 + l8;
            }
            gll16(asrc, &As[q * 2048 + w * 512]);
            const unsigned short* bsrc;
            if (BMODE == 0) {
                bsrc = Bm + (size_t)(bn + r) * ldb + kt + l8;
            } else {
                bsrc = Bm + (size_t)(tap * 1024 + bn + r) * 1024 + cin0 + l8;
            }
            gll16(bsrc, &Bs[q * 2048 + w * 512]);
        }
        __syncthreads();
#pragma unroll
        for (int ks = 0; ks < 2; ++ks) {
            const int kb = ks * 32 + (ln >> 4) * 8;
            short8 af[4], bf[4];
#pragma unroll
            for (int i = 0; i < 4; ++i)
                af[i] = *(const short8*)&As[(wm + i * 16 + (ln & 15)) * 64 + kb];
#pragma unroll
            for (int j = 0; j < 4; ++j)
                bf[j] = *(const short8*)&Bs[(wn + j * 16 + (ln & 15)) * 64 + kb];
#pragma unroll
            for (int i = 0; i < 4; ++i)
#pragma unroll
                for (int j = 0; j < 4; ++j)
                    acc[i][j] = __builtin_amdgcn_mfma_f32_16x16x32_bf16(
                        af[i], bf[j], acc[i][j], 0, 0, 0);
        }
        __syncthreads();
    }

    if constexpr (EPI == 4) {
        // top-2 per row within this wave's 64 cols, ranked (v desc, idx asc)
        const int g = blockIdx.x * 2 + (w & 1);   // col-group 0..63
#pragma unroll
        for (int i = 0; i < 4; ++i) {
#pragma unroll
            for (int r = 0; r < 4; ++r) {
                float v0 = -1e30f, v1 = -1e30f; int i0 = INT_MAX, i1 = INT_MAX;
#pragma unroll
                for (int j = 0; j < 4; ++j) {
                    const int col = bn + wn + j * 16 + (ln & 15);
                    float v = acc[i][j][r] + bias[col];
                    if (v > v0 || (v == v0 && col < i0)) { v1 = v0; i1 = i0; v0 = v; i0 = col; }
                    else if (v > v1 || (v == v1 && col < i1)) { v1 = v; i1 = col; }
                }
#pragma unroll
                for (int msk = 1; msk <= 8; msk <<= 1) {
                    float ov0 = __shfl_xor(v0, msk); int oi0 = __shfl_xor(i0, msk);
                    float ov1 = __shfl_xor(v1, msk); int oi1 = __shfl_xor(i1, msk);
                    if (ov0 > v0 || (ov0 == v0 && oi0 < i0)) {
                        if (v0 > ov1 || (v0 == ov1 && i0 < oi1)) { v1 = v0; i1 = i0; }
                        else { v1 = ov1; i1 = oi1; }
                        v0 = ov0; i0 = oi0;
                    } else {
                        if (ov0 > v1 || (ov0 == v1 && oi0 < i1)) { v1 = ov0; i1 = oi0; }
                    }
                }
                if ((ln & 15) == 0) {
                    const int row = bm + wm + i * 16 + (ln >> 4) * 4 + r;
                    size_t base = (size_t)row * 128 + g * 2;
                    cand_v[base] = v0; cand_v[base + 1] = v1;
                    cand_i[base] = i0; cand_i[base + 1] = i1;
                }
            }
        }
        return;
    }

    // epilogue: D row = (ln>>4)*4 + r, col = ln&15 within each 16x16 tile
#pragma unroll
    for (int i = 0; i < 4; ++i) {
        const int mrow = bm + wm + i * 16 + (ln >> 4) * 4;
#pragma unroll
        for (int j = 0; j < 4; ++j) {
            const int ncol = bn + wn + j * 16 + (ln & 15);
            const float bs = bias[ncol];
#pragma unroll
            for (int r = 0; r < 4; ++r) {
                const int m = mrow + r;
                float v = acc[i][j][r] + bs;
                if (EPI == 0) {
                    Cf[(size_t)m * ldc + coff + ncol] = v;
                } else if (EPI == 1) {
                    Cb[(size_t)m * ldc + coff + ncol] = f2bf(gelu_f(v));
                } else if (EPI == 2) {
                    Cb[(size_t)m * ldc + coff + ncol] = f2bf(v);
                } else if (EPI == 3) {
                    float g = gate[m];
                    size_t o = (size_t)m * 1024 + ncol;
                    Cf[o] = g * v + (1.0f - g) * Cf[o];
                }
            }
        }
    }
}

// ===========================================================================
// fp32 G1: inter = relu(x @ w1^T + b1), dual-write fp32 + bf16.
// 128x128 tile, BK=16, 256 threads, 8x8/thread, ds_read_b128 fragments.
// ===========================================================================
__global__ __launch_bounds__(256)
void gemm_relu2_k(const float* __restrict__ A, const float* __restrict__ Bm,
                  const float* __restrict__ bias,
                  float* __restrict__ C, unsigned short* __restrict__ Cb)
{
    __shared__ __align__(16) float As[16 * 132];
    __shared__ __align__(16) float Bs[16 * 132];
    const int tid = threadIdx.x;
    const int tx = tid & 15;
    const int ty = tid >> 4;
    const int bm = blockIdx.y * 128;
    const int bn = blockIdx.x * 128;

    float acc[8][8] = {};

    for (int kt = 0; kt < HD; kt += 16) {
#pragma unroll
        for (int l = 0; l < 2; ++l) {
            int idx = tid + l * 256;          // 0..511
            int m = idx >> 2;                 // 0..127
            int c4 = (idx & 3) * 4;           // 0,4,8,12
            float4 va = *(const float4*)&A[(size_t)(bm + m) * HD + kt + c4];
            As[(c4 + 0) * 132 + m] = va.x;
            As[(c4 + 1) * 132 + m] = va.y;
            As[(c4 + 2) * 132 + m] = va.z;
            As[(c4 + 3) * 132 + m] = va.w;
            float4 vb = *(const float4*)&Bm[(size_t)(bn + m) * HD + kt + c4];
            Bs[(c4 + 0) * 132 + m] = vb.x;
            Bs[(c4 + 1) * 132 + m] = vb.y;
            Bs[(c4 + 2) * 132 + m] = vb.z;
            Bs[(c4 + 3) * 132 + m] = vb.w;
        }
        __syncthreads();
#pragma unroll
        for (int c = 0; c < 16; ++c) {
            float4 a0 = *(const float4*)&As[c * 132 + ty * 8];
            float4 a1 = *(const float4*)&As[c * 132 + ty * 8 + 4];
            float4 b0 = *(const float4*)&Bs[c * 132 + tx * 8];
            float4 b1 = *(const float4*)&Bs[c * 132 + tx * 8 + 4];
            float a[8] = {a0.x, a0.y, a0.z, a0.w, a1.x, a1.y, a1.z, a1.w};
            float b[8] = {b0.x, b0.y, b0.z, b0.w, b1.x, b1.y, b1.z, b1.w};
#pragma unroll
            for (int i = 0; i < 8; ++i)
#pragma unroll
                for (int j = 0; j < 8; ++j)
                    acc[i][j] = fmaf(a[i], b[j], acc[i][j]);
        }
        __syncthreads();
    }

    float bs[8];
#pragma unroll
    for (int j = 0; j < 8; ++j) bs[j] = bias[bn + tx * 8 + j];
#pragma unroll
    for (int i = 0; i < 8; ++i) {
        const int m = bm + ty * 8 + i;
        float v[8];
#pragma unroll
        for (int j = 0; j < 8; ++j) v[j] = fmaxf(acc[i][j] + bs[j], 0.f);
        float* cp = C + (size_t)m * INTERD + bn + tx * 8;
        *(float4*)cp = make_float4(v[0], v[1], v[2], v[3]);
        *(float4*)(cp + 4) = make_float4(v[4], v[5], v[6], v[7]);
        unsigned u[4];
#pragma unroll
        for (int j = 0; j < 4; ++j)
            u[j] = (unsigned)f2bf(v[2 * j]) | ((unsigned)f2bf(v[2 * j + 1]) << 16);
        *(uint4*)(Cb + (size_t)m * INTERD + bn + tx * 8) =
            make_uint4(u[0], u[1], u[2], u[3]);
    }
}

// ===========================================================================
// rescore: wave-0 shuffle top-6 of 128 candidates -> all-thread fp32 dots ->
// reference-exact top-2 / softmax / usage / weighted_map (bf16 out).
// ===========================================================================
__global__ __launch_bounds__(128)
void rescore_k(const float* __restrict__ cand_v, const int* __restrict__ cand_i,
               const float* __restrict__ inter, const float* __restrict__ w2,
               const float* __restrict__ b2, const float* __restrict__ tptr,
               const float* __restrict__ pool,
               unsigned short* __restrict__ combined_b, float* __restrict__ usage)
{
    const int row = blockIdx.x;
    const int t = threadIdx.x;
    const int lane = t & 63;
    const int wv = t >> 6;
    __shared__ int   ssel[NCAND];
    __shared__ float pw[2][NCAND];
    __shared__ float wsh[2];
    __shared__ int   ish[2];

    // every thread: its 8 inter values (k = t + 128*q)
    float xr[8];
    const float* irow = inter + (size_t)row * INTERD;
#pragma unroll
    for (int q = 0; q < 8; ++q) xr[q] = irow[t + q * 128];

    // wave 0: top-NCAND selection from the 128 bf16 candidates
    if (wv == 0) {
        float v0 = cand_v[(size_t)row * 128 + lane];
        float v1 = cand_v[(size_t)row * 128 + 64 + lane];
        int   i0 = cand_i[(size_t)row * 128 + lane];
        int   i1 = cand_i[(size_t)row * 128 + 64 + lane];
        if (v1 > v0 || (v1 == v0 && i1 < i0)) {
            float tv = v0; v0 = v1; v1 = tv;
            int ti = i0; i0 = i1; i1 = ti;
        }
        for (int j = 0; j < NCAND; ++j) {
            float bv = v0; int bi = i0;
#pragma unroll
            for (int m = 32; m >= 1; m >>= 1) {
                float ov = __shfl_xor(bv, m);
                int oi = __shfl_xor(bi, m);
                if (ov > bv || (ov == bv && oi < bi)) { bv = ov; bi = oi; }
            }
            if (lane == 0) ssel[j] = bi;
            if (i0 == bi) { v0 = v1; i0 = i1; v1 = -1e30f; i1 = INT_MAX; }
        }
    }
    __syncthreads();

    int sel[NCAND];
#pragma unroll
    for (int j = 0; j < NCAND; ++j) sel[j] = ssel[j];
    float p[NCAND];
#pragma unroll
    for (int j = 0; j < NCAND; ++j) {
        const float* wr = w2 + (size_t)sel[j] * INTERD + t;
        float pj = 0.f;
#pragma unroll
        for (int q = 0; q < 8; ++q) pj = fmaf(xr[q], wr[q * 128], pj);
        p[j] = pj;
    }
#pragma unroll
    for (int j = 0; j < NCAND; ++j) {
#pragma unroll
        for (int m = 32; m >= 1; m >>= 1) p[j] += __shfl_xor(p[j], m);
    }
    if (lane == 0) {
#pragma unroll
        for (int j = 0; j < NCAND; ++j) pw[wv][j] = p[j];
    }
    __syncthreads();

    if (t == 0) {
        float tc = fminf(fmaxf(tptr[0], 0.1f), 5.0f);
        float bv0 = -1e30f, bv1 = -1e30f; int bi0 = INT_MAX, bi1 = INT_MAX;
        for (int j = 0; j < NCAND; ++j) {
            float logit = pw[0][j] + pw[1][j] + b2[sel[j]];
            float v = fminf(fmaxf(logit / tc, -10.f), 10.f);
            int n = sel[j];
            if (v > bv0 || (v == bv0 && n < bi0)) { bv1 = bv0; bi1 = bi0; bv0 = v; bi0 = n; }
            else if (v > bv1 || (v == bv1 && n < bi1)) { bv1 = v; bi1 = n; }
        }
        float e1 = expf(bv1 - bv0);
        float w0 = 1.f / (1.f + e1);
        float w1 = e1 / (1.f + e1);
        atomicAdd(&usage[bi0], w0);
        atomicAdd(&usage[bi1], w1);
        wsh[0] = w0; wsh[1] = w1; ish[0] = bi0; ish[1] = bi1;
    }
    __syncthreads();
    float w0 = wsh[0], w1 = wsh[1];
    const float* p0 = pool + (size_t)ish[0] * DD;
    const float* p1 = pool + (size_t)ish[1] * DD;
    unsigned short* dst = combined_b + (size_t)row * 1024 + 512;
#pragma unroll
    for (int q = 0; q < 4; ++q) {
        int j = t + q * 128;
        dst[j] = f2bf(w0 * p0[j] + w1 * p1[j]);
    }
}

// layernorm projx fp32 -> combined_b[:, :512] bf16
__global__ __launch_bounds__(256)
void ln_k(const float* __restrict__ projx, unsigned short* __restrict__ combined_b,
          const float* __restrict__ g, const float* __restrict__ b)
{
    int row = blockIdx.x;
    int t = threadIdx.x;
    const float* p = projx + (size_t)row * DD;
    float x0 = p[t], x1 = p[t + 256];
    __shared__ float s1[256], s2[256];
    s1[t] = x0 + x1;
    s2[t] = x0 * x0 + x1 * x1;
    __syncthreads();
    for (int o = 128; o > 0; o >>= 1) {
        if (t < o) { s1[t] += s1[t + o]; s2[t] += s2[t + o]; }
        __syncthreads();
    }
    float mu = s1[0] * (1.0f / 512.0f);
    float var = s2[0] * (1.0f / 512.0f) - mu * mu;
    float inv = rsqrtf(var + 1e-5f);
    unsigned short* dst = combined_b + (size_t)row * 1024;
    dst[t]       = f2bf((x0 - mu) * inv * g[t] + b[t]);
    dst[t + 256] = f2bf((x1 - mu) * inv * g[t + 256] + b[t + 256]);
}

__global__ __launch_bounds__(256)
void gate_k(const float* __restrict__ x, const float* __restrict__ wg,
            const float* __restrict__ bg, float* __restrict__ gate)
{
    int row = blockIdx.x;
    int t = threadIdx.x;
    const float* p = x + (size_t)row * HD;
    float s = p[t] * wg[t] + p[t + 256] * wg[t + 256]
            + p[t + 512] * wg[t + 512] + p[t + 768] * wg[t + 768];
    __shared__ float s1[256];
    s1[t] = s;
    __syncthreads();
    for (int o = 128; o > 0; o >>= 1) {
        if (t < o) s1[t] += s1[t + o];
        __syncthreads();
    }
    if (t == 0) gate[row] = 1.f / (1.f + expf(-(s1[0] + bg[0])));
}

__global__ __launch_bounds__(1024)
void divloss_k(const float* __restrict__ usage, float* __restrict__ out)
{
    int t = threadIdx.x;
    float u[4];
#pragma unroll
    for (int q = 0; q < 4; ++q) u[q] = usage[t + q * 1024];
    __shared__ float s1[1024];
    s1[t] = u[0] + u[1] + u[2] + u[3];
    __syncthreads();
    for (int o = 512; o > 0; o >>= 1) {
        if (t < o) s1[t] += s1[t + o];
        __syncthreads();
    }
    float inv = 1.0f / (s1[0] + 1e-8f);
    __syncthreads();
    float acc = 0.f;
#pragma unroll
    for (int q = 0; q < 4; ++q) {
        float d = u[q] * inv - (1.0f / 4096.0f);
        acc += d * d;
    }
    s1[t] = acc;
    __syncthreads();
    for (int o = 512; o > 0; o >>= 1) {
        if (t < o) s1[t] += s1[t + o];
        __syncthreads();
    }
    if (t == 0) out[(size_t)MR * HD] = s1[0] * (1.0f / 4096.0f) * 0.01f;
}

// ---- conversion kernels ----
__global__ __launch_bounds__(256)
void xpad_k(const float* __restrict__ x, unsigned short* __restrict__ xpad)
{
    size_t idx = (size_t)blockIdx.x * 256 + threadIdx.x;  // over 4*SP*1024
    int c = (int)(idx & 1023);
    int sp = (int)((idx >> 10) % SP);
    int b = (int)(idx / ((size_t)SP * 1024));
    float v = 0.f;
    if (sp >= 4 && sp < SQ + 4)
        v = x[((size_t)b * SQ + sp - 4) * 1024 + c];
    xpad[idx] = f2bf(v);
}

// conv_w [i][o][in][3] -> wconvb [i][tap][o][in]
__global__ __launch_bounds__(256)
void wconv_k(const float* __restrict__ cw, unsigned short* __restrict__ wb)
{
    size_t idx = (size_t)blockIdx.x * 256 + threadIdx.x;  // over 9*1024*1024
    int it = (int)(idx >> 20);       // i*3+tap
    int i = it / 3, tap = it % 3;
    int o = (int)((idx >> 10) & 1023);
    int in = (int)(idx & 1023);
    wb[idx] = f2bf(cw[(((size_t)(i * 1024 + o)) * 1024 + in) * 3 + tap]);
}

__global__ __launch_bounds__(256)
void cvt_k(const float* __restrict__ src, unsigned short* __restrict__ dst, int n)
{
    int idx = blockIdx.x * 256 + threadIdx.x;
    if (idx < n) dst[idx] = f2bf(src[idx]);
}

extern "C" void kernel_launch(void* const* d_in, const int* in_sizes, int n_in,
                              void* d_out, int out_size, void* d_ws, size_t ws_size,
                              hipStream_t stream)
{
    const float* x     = (const float*)d_in[0];
    const float* pool  = (const float*)d_in[1];
    const float* w1    = (const float*)d_in[2];
    const float* b1    = (const float*)d_in[3];
    const float* w2    = (const float*)d_in[4];
    const float* b2    = (const float*)d_in[5];
    const float* temp  = (const float*)d_in[6];
    const float* wproj = (const float*)d_in[7];
    const float* bproj = (const float*)d_in[8];
    const float* ln_g  = (const float*)d_in[9];
    const float* ln_b  = (const float*)d_in[10];
    const float* wmap  = (const float*)d_in[11];
    const float* bmap  = (const float*)d_in[12];
    const float* convw = (const float*)d_in[13];
    const float* convb = (const float*)d_in[14];
    const float* wout  = (const float*)d_in[15];
    const float* bout  = (const float*)d_in[16];
    const float* wrp   = (const float*)d_in[17];
    const float* brp   = (const float*)d_in[18];
    const float* wg    = (const float*)d_in[19];
    const float* bg    = (const float*)d_in[20];
    float* out = (float*)d_out;

    char* w8 = (char*)d_ws;
    float*          inter      = (float*)(w8 + 0);                  // 67.1 MB fp32 [until rescore]
    unsigned short* inter_b    = (unsigned short*)(w8 + 67108864);  // 33.6 MB bf16 [until G2cand done]
    unsigned short* concat     = (unsigned short*)(w8 + 0);         // 100.7 MB, aliases inter+inter_b (conv phase)
    float*          projx      = (float*)(w8 + 100663296);          // 33.6 MB
    unsigned short* combined_b = (unsigned short*)(w8 + 134217728); // 33.6 MB
    unsigned short* trans_b    = (unsigned short*)(w8 + 167772160); // 16.8 MB
    float*          cand_v     = (float*)(w8 + 184549376);          // 8.4 MB  [until rescore]
    int*            cand_i     = (int*)(w8 + 192937984);            // 8.4 MB  [until rescore]
    unsigned short* xpad       = (unsigned short*)(w8 + 184549376); // 33.6 MB, aliases cand (after rescore)
    unsigned short* wconvb     = (unsigned short*)(w8 + 218169344); // 18.9 MB
    unsigned short* woutb      = (unsigned short*)(w8 + 237043712); // 6.3 MB
    unsigned short* w2b        = (unsigned short*)(w8 + 237043712); // 8.4 MB, aliases wout/wmap/wrp slots (early)
    unsigned short* wmapb      = (unsigned short*)(w8 + 243335168); // 1.0 MB
    unsigned short* wrpb       = (unsigned short*)(w8 + 244383744); // 1.0 MB
    unsigned short* wprojb     = (unsigned short*)(w8 + 245432320); // 1.0 MB
    float*          gate       = (float*)(w8 + 246480896);          // 64 KB
    float*          usage      = (float*)(w8 + 246546432);          // 16 KB

    hipMemsetAsync(usage, 0, PD * sizeof(float), stream);

    dim3 blk(256);
    // --- router ---
    // G1: inter = relu(x@w1^T+b1), fp32 + bf16 (exact fp32 path for rescore)
    gemm_relu2_k<<<dim3(8, 128), blk, 0, stream>>>(x, w1, b1, inter, inter_b);
    // w2 -> bf16 (region reused by wout/wmap/wrp later)
    cvt_k<<<dim3((PD * INTERD + 255) / 256), blk, 0, stream>>>(w2, w2b, PD * INTERD);
    // G2cand: bf16 MFMA logits, top-2 per 64-col group
    bgemm_k<0, 0, 4><<<dim3(32, 128), blk, 0, stream>>>(inter_b, INTERD, w2b, INTERD,
        b2, nullptr, nullptr, 0, 0, INTERD, 0, nullptr, cand_v, cand_i);
    // exact fp32 rescore + selection + weighted_map + usage
    rescore_k<<<dim3(MR), dim3(128), 0, stream>>>(cand_v, cand_i, inter, w2, b2,
        temp, pool, combined_b, usage);

    // --- conversions (cand + inter regions dead; aliases safe) ---
    xpad_k<<<dim3((4 * SP * 1024) / 256), blk, 0, stream>>>(x, xpad);
    wconv_k<<<dim3((9 * 1024 * 1024) / 256), blk, 0, stream>>>(convw, wconvb);
    cvt_k<<<dim3((1024 * 3072 + 255) / 256), blk, 0, stream>>>(wout, woutb, 1024 * 3072);
    cvt_k<<<dim3((512 * 1024 + 255) / 256), blk, 0, stream>>>(wmap, wmapb, 512 * 1024);
    cvt_k<<<dim3((1024 * 512 + 255) / 256), blk, 0, stream>>>(wrp, wrpb, 1024 * 512);
    cvt_k<<<dim3((512 * 1024 + 255) / 256), blk, 0, stream>>>(wproj, wprojb, 512 * 1024);

    // --- global branch (bf16 MFMA) ---
    bgemm_k<1, 0, 0><<<dim3(4, 128), blk, 0, stream>>>(xpad, 0, wprojb, HD, bproj,
        projx, nullptr, DD, 0, HD, 0, nullptr, nullptr, nullptr);
    ln_k<<<dim3(MR), dim3(256), 0, stream>>>(projx, combined_b, ln_g, ln_b);
    bgemm_k<0, 0, 2><<<dim3(4, 128), blk, 0, stream>>>(combined_b, 1024, wmapb, 1024,
        bmap, nullptr, trans_b, DD, 0, 1024, 0, nullptr, nullptr, nullptr);
    bgemm_k<0, 0, 0><<<dim3(8, 128), blk, 0, stream>>>(trans_b, DD, wrpb, DD, brp,
        out, nullptr, HD, 0, DD, 0, nullptr, nullptr, nullptr);
    gate_k<<<dim3(MR), dim3(256), 0, stream>>>(x, wg, bg, gate);
    divloss_k<<<dim3(1), dim3(1024), 0, stream>>>(usage, out);

    // --- local branch (bf16 MFMA) ---
    const int dils[3] = {1, 2, 4};
    for (int i = 0; i < 3; ++i) {
        bgemm_k<1, 1, 1><<<dim3(8, 128), blk, 0, stream>>>(
            xpad, 0, wconvb + (size_t)i * 3 * 1024 * 1024, 0,
            convb + (size_t)i * HD,
            nullptr, concat, 3072, i * 1024, 3072, dils[i], nullptr, nullptr, nullptr);
    }
    // wout GEMM with fused gate-combine: out = g*local + (1-g)*out
    bgemm_k<0, 0, 3><<<dim3(8, 128), blk, 0, stream>>>(concat, 3072, woutb, 3072,
        bout, out, nullptr, HD, 0, 3072, 0, gate, nullptr, nullptr);
}